// Round 12
// baseline (2745.767 us; speedup 1.0000x reference)
//
#include <hip/hip_runtime.h>
#include <hip/hip_bf16.h>

#define EMB 768
#define HID 3072
#define HID2 6144
#define NE 8
#define TOK 16384    // B*N = 8*2048
#define SLOTS 32768  // TOK * top-2
#define SLACK 256    // tail-read slack rows (M-tile 256 may overrun by 255)
#define MAXTILES 136 // max active M-tiles: 128 + (NE-1) partials

typedef __attribute__((ext_vector_type(8))) short bf16x8;
typedef __attribute__((ext_vector_type(4))) float f32x4;

__device__ __forceinline__ unsigned short bfbits(float f) {
  __hip_bfloat16 h = __float2bfloat16(f);
  return __builtin_bit_cast(unsigned short, h);
}

// ---------------- init / gating / routing ----------------

__global__ void k_init(int* counts, int* fill) {
  if (threadIdx.x < NE) { counts[threadIdx.x] = 0; fill[threadIdx.x] = 0; }
}

__global__ __launch_bounds__(256) void k_gating(
    const float* __restrict__ x, const float* __restrict__ Wg,
    const float* __restrict__ bg, int* __restrict__ eidx,
    float* __restrict__ gates)
{
  const int wave = threadIdx.x >> 6, lane = threadIdx.x & 63;
  const int t = blockIdx.x * 4 + wave;
  const float* xr = x + (size_t)t * EMB;
  float p[NE];
#pragma unroll
  for (int e = 0; e < NE; ++e) p[e] = 0.f;
  for (int k = lane; k < EMB; k += 64) {
    const float xv = xr[k];
    const float* wr = Wg + (size_t)k * NE;
#pragma unroll
    for (int e = 0; e < NE; ++e) p[e] += xv * wr[e];
  }
#pragma unroll
  for (int e = 0; e < NE; ++e) {
#pragma unroll
    for (int o = 32; o > 0; o >>= 1) p[e] += __shfl_xor(p[e], o);
    p[e] += bg[e];
  }
  float v0 = -1e30f, v1 = -1e30f; int i0 = 0, i1 = 0;
#pragma unroll
  for (int e = 0; e < NE; ++e) {
    const float v = p[e];
    if (v > v0)      { v1 = v0; i1 = i0; v0 = v; i0 = e; }
    else if (v > v1) { v1 = v;  i1 = e; }
  }
  const float ex = expf(v1 - v0);
  const float g0 = 1.f / (1.f + ex);
  const float g1 = 1.f - g0;
  if (lane == 0) {
    eidx[2*t] = i0; eidx[2*t+1] = i1;
    gates[2*t] = g0; gates[2*t+1] = g1;
  }
}

__global__ __launch_bounds__(256) void k_count(const int* __restrict__ eidx,
                                               int* __restrict__ counts)
{
  __shared__ int bins[NE];
  if (threadIdx.x < NE) bins[threadIdx.x] = 0;
  __syncthreads();
  const int base = blockIdx.x * 512 + threadIdx.x * 2;
  atomicAdd(&bins[eidx[base]], 1);
  atomicAdd(&bins[eidx[base + 1]], 1);
  __syncthreads();
  if (threadIdx.x < NE) atomicAdd(&counts[threadIdx.x], bins[threadIdx.x]);
}

__global__ void k_offsets(const int* __restrict__ counts, int* __restrict__ offsets,
                          int* __restrict__ tmap)
{
  offsets[0] = 0;
  int idx = 0;
  for (int e = 0; e < NE; ++e) {
    offsets[e+1] = offsets[e] + counts[e];
    const int nt = (counts[e] + 255) >> 8;
    for (int i = 0; i < nt; ++i) tmap[idx++] = (e << 16) | i;
  }
  for (; idx < MAXTILES; ++idx) tmap[idx] = -1;
}

__global__ __launch_bounds__(256) void k_route(
    const int* __restrict__ eidx, int* __restrict__ fill,
    const int* __restrict__ offsets, int* __restrict__ route_tok,
    float* __restrict__ gate_slot, int* __restrict__ tok_k,
    const float* __restrict__ gates)
{
  __shared__ int bins[NE], base[NE];
  const int tid = threadIdx.x;
  if (tid < NE) bins[tid] = 0;
  __syncthreads();
  const int t = blockIdx.x * 256 + tid;
  int e0 = eidx[2*t], e1 = eidx[2*t+1];
  int lp0 = atomicAdd(&bins[e0], 1);
  int lp1 = atomicAdd(&bins[e1], 1);
  __syncthreads();
  if (tid < NE) base[tid] = atomicAdd(&fill[tid], bins[tid]);
  __syncthreads();
  const int s0 = offsets[e0] + base[e0] + lp0;
  const int s1 = offsets[e1] + base[e1] + lp1;
  route_tok[s0] = t;          route_tok[s1] = t;
  gate_slot[s0] = gates[2*t]; gate_slot[s1] = gates[2*t+1];
  tok_k[s0] = 2*t;            tok_k[s1] = 2*t + 1;
}

__global__ __launch_bounds__(256) void k_gather(
    const float* __restrict__ x, const int* __restrict__ route_tok,
    __hip_bfloat16* __restrict__ xg)
{
  const int w = threadIdx.x >> 6, lane = threadIdx.x & 63;
  const int s = blockIdx.x * 4 + w;
  const int t = route_tok[s];
  const float4* src = (const float4*)(x + (size_t)t * EMB);
  unsigned short* dst = (unsigned short*)xg + (size_t)s * EMB;
#pragma unroll
  for (int i = 0; i < 3; ++i) {
    const float4 v = src[lane + 64 * i];
    ushort4 u;
    u.x = bfbits(v.x); u.y = bfbits(v.y); u.z = bfbits(v.z); u.w = bfbits(v.w);
    *(ushort4*)(dst + (lane + 64 * i) * 4) = u;
  }
}

// unified fp32 [K,N] -> bf16 [N,K] transpose, 64x64 tiles
#define NT1 (NE * (HID  / 64) * (EMB  / 64))   // 4608
#define NT2 (NE * (HID2 / 64) * (HID  / 64))   // 36864
#define NT3 (NE * (EMB  / 64) * (HID2 / 64))   // 9216

typedef __attribute__((ext_vector_type(8))) unsigned short u16x8;

__global__ __launch_bounds__(256) void k_transpose_all(
    const float* __restrict__ W1, const float* __restrict__ W2,
    const float* __restrict__ W3, __hip_bfloat16* __restrict__ Wb1,
    __hip_bfloat16* __restrict__ Wb2, __hip_bfloat16* __restrict__ Wb3)
{
  __shared__ float tile[64][65];   // [k][n]
  int bid = blockIdx.x;
  const float* W; __hip_bfloat16* Wt; int K, N;
  if (bid < NT1)              { W = W1; Wt = Wb1; K = EMB;  N = HID;  }
  else if (bid < NT1 + NT2)   { W = W2; Wt = Wb2; K = HID;  N = HID2; bid -= NT1; }
  else                        { W = W3; Wt = Wb3; K = HID2; N = EMB;  bid -= NT1 + NT2; }
  const int ntn = N >> 6, ntk = K >> 6;
  const int e  = bid / (ntn * ntk);
  const int rem = bid - e * (ntn * ntk);
  const int k0 = (rem / ntn) << 6;
  const int n0 = (rem % ntn) << 6;

  const float* Wp = W + (size_t)e * K * N;
  __hip_bfloat16* Wtp = Wt + (size_t)e * K * N;
  const int tx = threadIdx.x, ty = threadIdx.y;   // 32 x 8

  const int q = tx & 15, rsub = tx >> 4;
#pragma unroll
  for (int it = 0; it < 4; ++it) {
    const int r = it * 16 + ty * 2 + rsub;
    const float4 v = *(const float4*)(Wp + (size_t)(k0 + r) * N + n0 + 4 * q);
    tile[r][4 * q]     = v.x;
    tile[r][4 * q + 1] = v.y;
    tile[r][4 * q + 2] = v.z;
    tile[r][4 * q + 3] = v.w;
  }
  __syncthreads();
  const int q8 = tx & 7, r8 = tx >> 3;
#pragma unroll
  for (int it = 0; it < 2; ++it) {
    const int n = it * 32 + ty * 4 + r8;
    u16x8 u;
#pragma unroll
    for (int j = 0; j < 8; ++j) u[j] = bfbits(tile[8 * q8 + j][n]);
    *(u16x8*)((unsigned short*)Wtp + (size_t)(n0 + n) * K + k0 + 8 * q8) = u;
  }
}

// ---- 256x256 MFMA GEMM, 4-half-unit rotation, cross-phase read-ahead ------
// (R11 structure verbatim.) KLEN = K-slice length (== K unless split-K);
// blockIdx.z selects the K-slice. ATOMIC epilogue (stage-3 split-K):
// atomicAdd(out + tok*EMB + col, g*(acc + bias@kslice0)) — 8 fp32 adds per
// out element, reassociation noise ~1e-6 << 0.035 threshold.

#define BARRIER() asm volatile("s_barrier" ::: "memory")
#define LGKM(n) { asm volatile("s_waitcnt lgkmcnt(" #n ")" ::: "memory"); __builtin_amdgcn_sched_barrier(0); }
#define VMC(n)  { asm volatile("s_waitcnt vmcnt(" #n ")" ::: "memory"); __builtin_amdgcn_sched_barrier(0); }

template<bool GELU, bool OUTBF, bool ATOMIC>
__global__ __launch_bounds__(512) void ffn_gemm8(
    const __hip_bfloat16* __restrict__ A,
    const __hip_bfloat16* __restrict__ Bt,
    const float* __restrict__ bias,
    void* __restrict__ Cout,
    const int* __restrict__ counts,
    const int* __restrict__ offsets,
    const int* __restrict__ tmap,
    const float* __restrict__ gate_slot,
    const int* __restrict__ tok_k,
    int K, int N, int KLEN)
{
  const int me = tmap[blockIdx.y];
  if (me < 0) return;
  const int e  = me >> 16;
  const int m0 = (me & 0xffff) << 8;
  const int cnt = counts[e];
  const int seg = offsets[e];
  const int n0 = blockIdx.x * 256;
  const int kbase = blockIdx.z * KLEN * 2;   // byte offset of this K-slice

  __shared__ char lds[131072];

  const int tid = threadIdx.x;
  const int wave = tid >> 6, lane = tid & 63;
  const int wm = wave >> 2, wn = wave & 3;

  const size_t KB = (size_t)K * 2;           // global row stride bytes
  const char* Ag = (const char*)(A + (size_t)(seg + m0) * K);
  const char* Bg = (const char*)(Bt + (size_t)e * N * K + (size_t)n0 * K);

  const int s_r  = tid >> 2;                                    // 0..127
  const int s_cb = ((tid & 3) * 16) ^ (((s_r >> 1) & 3) << 4);  // src pre-swizzle

  auto S = [&](int x) {
    const int ub = (x & 3) * 32768;
    const int kbyte = kbase + x * 64;
    const char* sa = Ag + (size_t)s_r * KB + kbyte + s_cb;
    const char* sb = Bg + (size_t)s_r * KB + kbyte + s_cb;
    __builtin_amdgcn_global_load_lds(
        (const __attribute__((address_space(1))) void*)sa,
        (__attribute__((address_space(3))) void*)(lds + ub + tid * 16), 16, 0, 0);
    __builtin_amdgcn_global_load_lds(
        (const __attribute__((address_space(1))) void*)(sa + 128 * KB),
        (__attribute__((address_space(3))) void*)(lds + ub + 8192 + tid * 16), 16, 0, 0);
    __builtin_amdgcn_global_load_lds(
        (const __attribute__((address_space(1))) void*)sb,
        (__attribute__((address_space(3))) void*)(lds + ub + 16384 + tid * 16), 16, 0, 0);
    __builtin_amdgcn_global_load_lds(
        (const __attribute__((address_space(1))) void*)(sb + 128 * KB),
        (__attribute__((address_space(3))) void*)(lds + ub + 16384 + 8192 + tid * 16), 16, 0, 0);
  };

  const int fr    = lane & 15;
  const int coff  = ((lane >> 4) * 16) ^ (((fr >> 1) & 3) << 4);
  const int aoff0 = (wm * 128 + fr) * 64 + coff;
  const int boff0 = 16384 + (wn * 64 + fr) * 64 + coff;

  f32x4 acc[8][4];
#pragma unroll
  for (int i = 0; i < 8; ++i)
#pragma unroll
    for (int j = 0; j < 4; ++j)
      acc[i][j] = (f32x4){0.f, 0.f, 0.f, 0.f};

  const int NPH = KLEN >> 5;

  bf16x8 aE[8], bE[4], aO[8], bO[4];

#define RD(x, as, bs) {                                             \
    const char* ub_ = lds + ((x) & 3) * 32768;                      \
    _Pragma("unroll")                                               \
    for (int m_ = 0; m_ < 8; ++m_)                                  \
      as[m_] = *(const bf16x8*)(ub_ + aoff0 + m_ * 1024);           \
    _Pragma("unroll")                                               \
    for (int n_ = 0; n_ < 4; ++n_)                                  \
      bs[n_] = *(const bf16x8*)(ub_ + boff0 + n_ * 1024); }

#define MM(as, bs) {                                                \
    _Pragma("unroll")                                               \
    for (int m_ = 0; m_ < 8; ++m_)                                  \
      _Pragma("unroll")                                             \
      for (int n_ = 0; n_ < 4; ++n_)                                \
        acc[m_][n_] = __builtin_amdgcn_mfma_f32_16x16x32_bf16(      \
            as[m_], bs[n_], acc[m_][n_], 0, 0, 0); }

  S(0); S(1);
  VMC(4);
  BARRIER();

  RD(0, aE, bE);
  S(2);
  VMC(4);
  BARRIER();

  RD(1, aO, bO);
  S(3);
  LGKM(12);
  MM(aE, bE);
  VMC(4);
  BARRIER();

  for (int p = 2; p < NPH; p += 2) {
    RD(p, aE, bE);
    S(p + 2 < NPH ? p + 2 : NPH - 1);
    LGKM(12);
    MM(aO, bO);
    VMC(4);
    BARRIER();
    RD(p + 1, aO, bO);
    S(p + 3 < NPH ? p + 3 : NPH - 1);
    LGKM(12);
    MM(aE, bE);
    VMC(4);
    BARRIER();
  }

  LGKM(0);
  MM(aO, bO);

#undef RD
#undef MM

  // ---- epilogue: C/D map col=lane&15, row=(lane>>4)*4+r  [m89-verified]
#pragma unroll
  for (int mf = 0; mf < 8; ++mf) {
#pragma unroll
    for (int r2 = 0; r2 < 4; ++r2) {
      const int gm = m0 + wm * 128 + mf * 16 + (lane >> 4) * 4 + r2;
      if (gm >= cnt) continue;
      if (ATOMIC) {
        const int s = seg + gm;
        const float g = gate_slot[s];
        const int tok = tok_k[s] >> 1;
        float* dst = (float*)Cout + (size_t)tok * EMB;
        const bool addb = (blockIdx.z == 0);
#pragma unroll
        for (int nf = 0; nf < 4; ++nf) {
          const int gcol = n0 + wn * 64 + nf * 16 + fr;
          const float v = acc[mf][nf][r2] + (addb ? bias[(size_t)e * N + gcol] : 0.f);
          atomicAdd(&dst[gcol], g * v);
        }
      } else {
#pragma unroll
        for (int nf = 0; nf < 4; ++nf) {
          const int gcol = n0 + wn * 64 + nf * 16 + fr;
          float v = acc[mf][nf][r2] + bias[(size_t)e * N + gcol];
          if (GELU) v = 0.5f * v * (1.0f + erff(v * 0.70710678118654752f));
          if (OUTBF)
            ((__hip_bfloat16*)Cout)[(size_t)(seg + gm) * N + gcol] = __float2bfloat16(v);
          else
            ((float*)Cout)[(size_t)(seg + gm) * N + gcol] = v;
        }
      }
    }
  }
}

// ---------------- launch ----------------

extern "C" void kernel_launch(void* const* d_in, const int* in_sizes, int n_in,
                              void* d_out, int out_size, void* d_ws, size_t ws_size,
                              hipStream_t stream)
{
  const float* x  = (const float*)d_in[0];
  const float* Wg = (const float*)d_in[1];
  const float* bg = (const float*)d_in[2];
  const float* W1 = (const float*)d_in[3];
  const float* b1 = (const float*)d_in[4];
  const float* W2 = (const float*)d_in[5];
  const float* b2 = (const float*)d_in[6];
  const float* W3 = (const float*)d_in[7];
  const float* b3 = (const float*)d_in[8];
  float* out = (float*)d_out;

  char* ws = (char*)d_ws;
  size_t off = 0;
  auto alloc = [&](size_t bytes) -> void* {
    void* p = ws + off;
    off = (off + bytes + 255) & ~(size_t)255;
    return p;
  };

  int*   counts    = (int*)alloc(NE * 4);
  int*   fill      = (int*)alloc(NE * 4);
  int*   offsets   = (int*)alloc((NE + 1) * 4);
  int*   tmap      = (int*)alloc(MAXTILES * 4);
  int*   eidx      = (int*)alloc((size_t)TOK * 2 * 4);
  float* gates     = (float*)alloc((size_t)TOK * 2 * 4);
  int*   route_tok = (int*)alloc((size_t)SLOTS * 4);
  float* gate_slot = (float*)alloc((size_t)(SLOTS + SLACK) * 4);
  int*   tok_k     = (int*)alloc((size_t)(SLOTS + SLACK) * 4);
  __hip_bfloat16* Wb1 = (__hip_bfloat16*)alloc((size_t)NE * EMB  * HID  * 2);
  __hip_bfloat16* Wb2 = (__hip_bfloat16*)alloc((size_t)NE * HID  * HID2 * 2);
  __hip_bfloat16* Wb3 = (__hip_bfloat16*)alloc((size_t)NE * HID2 * EMB  * 2);
  __hip_bfloat16* xg  = (__hip_bfloat16*)alloc((size_t)(SLOTS + SLACK) * EMB  * 2);
  __hip_bfloat16* h1  = (__hip_bfloat16*)alloc((size_t)(SLOTS + SLACK) * HID  * 2);
  __hip_bfloat16* h2  = (__hip_bfloat16*)alloc((size_t)(SLOTS + SLACK) * HID2 * 2);
  (void)ws_size; (void)in_sizes; (void)n_in;

  hipMemsetAsync(d_out, 0, (size_t)out_size * 4, stream);

  k_init<<<1, 64, 0, stream>>>(counts, fill);
  k_gating<<<TOK / 4, 256, 0, stream>>>(x, Wg, bg, eidx, gates);
  k_count<<<SLOTS / 512, 256, 0, stream>>>(eidx, counts);
  k_offsets<<<1, 1, 0, stream>>>(counts, offsets, tmap);
  k_route<<<TOK / 256, 256, 0, stream>>>(eidx, fill, offsets, route_tok,
                                         gate_slot, tok_k, gates);
  k_gather<<<SLOTS / 4, 256, 0, stream>>>(x, route_tok, xg);

  k_transpose_all<<<NT1 + NT2 + NT3, dim3(32, 8), 0, stream>>>(W1, W2, W3, Wb1, Wb2, Wb3);

  ffn_gemm8<true,  true,  false><<<dim3(HID  / 256, MAXTILES), 512, 0, stream>>>(
      xg, Wb1, b1, h1, counts, offsets, tmap, nullptr, nullptr, EMB,  HID,  EMB);
  ffn_gemm8<true,  true,  false><<<dim3(HID2 / 256, MAXTILES), 512, 0, stream>>>(
      h1, Wb2, b2, h2, counts, offsets, tmap, nullptr, nullptr, HID,  HID2, HID);
  ffn_gemm8<false, false, true ><<<dim3(EMB  / 256, MAXTILES, 4), 512, 0, stream>>>(
      h2, Wb3, b3, out, counts, offsets, tmap, gate_slot, tok_k, HID2, EMB, HID2 / 4);
}

// Round 13
// 2518.021 us; speedup vs baseline: 1.0904x; 1.0904x over previous
//
#include <hip/hip_runtime.h>
#include <hip/hip_bf16.h>

#define EMB 768
#define HID 3072
#define HID2 6144
#define NE 8
#define TOK 16384    // B*N = 8*2048
#define SLOTS 32768  // TOK * top-2
#define SLACK 256    // tail-read slack rows (M-tile 256 may overrun by 255)
#define MAXTILES 136 // max active M-tiles: 128 + (NE-1) partials

typedef __attribute__((ext_vector_type(8))) short bf16x8;
typedef __attribute__((ext_vector_type(4))) float f32x4;

__device__ __forceinline__ unsigned short bfbits(float f) {
  __hip_bfloat16 h = __float2bfloat16(f);
  return __builtin_bit_cast(unsigned short, h);
}

// ---------------- init / gating / routing ----------------

__global__ void k_init(int* counts, int* fill) {
  if (threadIdx.x < NE) { counts[threadIdx.x] = 0; fill[threadIdx.x] = 0; }
}

__global__ __launch_bounds__(256) void k_gating(
    const float* __restrict__ x, const float* __restrict__ Wg,
    const float* __restrict__ bg, int* __restrict__ eidx,
    float* __restrict__ gates)
{
  const int wave = threadIdx.x >> 6, lane = threadIdx.x & 63;
  const int t = blockIdx.x * 4 + wave;
  const float* xr = x + (size_t)t * EMB;
  float p[NE];
#pragma unroll
  for (int e = 0; e < NE; ++e) p[e] = 0.f;
  for (int k = lane; k < EMB; k += 64) {
    const float xv = xr[k];
    const float* wr = Wg + (size_t)k * NE;
#pragma unroll
    for (int e = 0; e < NE; ++e) p[e] += xv * wr[e];
  }
#pragma unroll
  for (int e = 0; e < NE; ++e) {
#pragma unroll
    for (int o = 32; o > 0; o >>= 1) p[e] += __shfl_xor(p[e], o);
    p[e] += bg[e];
  }
  float v0 = -1e30f, v1 = -1e30f; int i0 = 0, i1 = 0;
#pragma unroll
  for (int e = 0; e < NE; ++e) {
    const float v = p[e];
    if (v > v0)      { v1 = v0; i1 = i0; v0 = v; i0 = e; }
    else if (v > v1) { v1 = v;  i1 = e; }
  }
  const float ex = expf(v1 - v0);
  const float g0 = 1.f / (1.f + ex);
  const float g1 = 1.f - g0;
  if (lane == 0) {
    eidx[2*t] = i0; eidx[2*t+1] = i1;
    gates[2*t] = g0; gates[2*t+1] = g1;
  }
}

__global__ __launch_bounds__(256) void k_count(const int* __restrict__ eidx,
                                               int* __restrict__ counts)
{
  __shared__ int bins[NE];
  if (threadIdx.x < NE) bins[threadIdx.x] = 0;
  __syncthreads();
  const int base = blockIdx.x * 512 + threadIdx.x * 2;
  atomicAdd(&bins[eidx[base]], 1);
  atomicAdd(&bins[eidx[base + 1]], 1);
  __syncthreads();
  if (threadIdx.x < NE) atomicAdd(&counts[threadIdx.x], bins[threadIdx.x]);
}

__global__ void k_offsets(const int* __restrict__ counts, int* __restrict__ offsets,
                          int* __restrict__ tmap)
{
  offsets[0] = 0;
  int idx = 0;
  for (int e = 0; e < NE; ++e) {
    offsets[e+1] = offsets[e] + counts[e];
    const int nt = (counts[e] + 255) >> 8;
    for (int i = 0; i < nt; ++i) tmap[idx++] = (e << 16) | i;
  }
  for (; idx < MAXTILES; ++idx) tmap[idx] = -1;
}

__global__ __launch_bounds__(256) void k_route(
    const int* __restrict__ eidx, int* __restrict__ fill,
    const int* __restrict__ offsets, int* __restrict__ route_tok,
    float* __restrict__ gate_slot, int* __restrict__ tok_k,
    const float* __restrict__ gates)
{
  __shared__ int bins[NE], base[NE];
  const int tid = threadIdx.x;
  if (tid < NE) bins[tid] = 0;
  __syncthreads();
  const int t = blockIdx.x * 256 + tid;
  int e0 = eidx[2*t], e1 = eidx[2*t+1];
  int lp0 = atomicAdd(&bins[e0], 1);
  int lp1 = atomicAdd(&bins[e1], 1);
  __syncthreads();
  if (tid < NE) base[tid] = atomicAdd(&fill[tid], bins[tid]);
  __syncthreads();
  const int s0 = offsets[e0] + base[e0] + lp0;
  const int s1 = offsets[e1] + base[e1] + lp1;
  route_tok[s0] = t;          route_tok[s1] = t;
  gate_slot[s0] = gates[2*t]; gate_slot[s1] = gates[2*t+1];
  tok_k[s0] = 2*t;            tok_k[s1] = 2*t + 1;
}

__global__ __launch_bounds__(256) void k_gather(
    const float* __restrict__ x, const int* __restrict__ route_tok,
    __hip_bfloat16* __restrict__ xg)
{
  const int w = threadIdx.x >> 6, lane = threadIdx.x & 63;
  const int s = blockIdx.x * 4 + w;
  const int t = route_tok[s];
  const float4* src = (const float4*)(x + (size_t)t * EMB);
  unsigned short* dst = (unsigned short*)xg + (size_t)s * EMB;
#pragma unroll
  for (int i = 0; i < 3; ++i) {
    const float4 v = src[lane + 64 * i];
    ushort4 u;
    u.x = bfbits(v.x); u.y = bfbits(v.y); u.z = bfbits(v.z); u.w = bfbits(v.w);
    *(ushort4*)(dst + (lane + 64 * i) * 4) = u;
  }
}

// unified fp32 [K,N] -> bf16 [N,K] transpose, 64x64 tiles
#define NT1 (NE * (HID  / 64) * (EMB  / 64))   // 4608
#define NT2 (NE * (HID2 / 64) * (HID  / 64))   // 36864
#define NT3 (NE * (EMB  / 64) * (HID2 / 64))   // 9216

typedef __attribute__((ext_vector_type(8))) unsigned short u16x8;

__global__ __launch_bounds__(256) void k_transpose_all(
    const float* __restrict__ W1, const float* __restrict__ W2,
    const float* __restrict__ W3, __hip_bfloat16* __restrict__ Wb1,
    __hip_bfloat16* __restrict__ Wb2, __hip_bfloat16* __restrict__ Wb3)
{
  __shared__ float tile[64][65];   // [k][n]
  int bid = blockIdx.x;
  const float* W; __hip_bfloat16* Wt; int K, N;
  if (bid < NT1)              { W = W1; Wt = Wb1; K = EMB;  N = HID;  }
  else if (bid < NT1 + NT2)   { W = W2; Wt = Wb2; K = HID;  N = HID2; bid -= NT1; }
  else                        { W = W3; Wt = Wb3; K = HID2; N = EMB;  bid -= NT1 + NT2; }
  const int ntn = N >> 6, ntk = K >> 6;
  const int e  = bid / (ntn * ntk);
  const int rem = bid - e * (ntn * ntk);
  const int k0 = (rem / ntn) << 6;
  const int n0 = (rem % ntn) << 6;

  const float* Wp = W + (size_t)e * K * N;
  __hip_bfloat16* Wtp = Wt + (size_t)e * K * N;
  const int tx = threadIdx.x, ty = threadIdx.y;   // 32 x 8

  const int q = tx & 15, rsub = tx >> 4;
#pragma unroll
  for (int it = 0; it < 4; ++it) {
    const int r = it * 16 + ty * 2 + rsub;
    const float4 v = *(const float4*)(Wp + (size_t)(k0 + r) * N + n0 + 4 * q);
    tile[r][4 * q]     = v.x;
    tile[r][4 * q + 1] = v.y;
    tile[r][4 * q + 2] = v.z;
    tile[r][4 * q + 3] = v.w;
  }
  __syncthreads();
  const int q8 = tx & 7, r8 = tx >> 3;
#pragma unroll
  for (int it = 0; it < 2; ++it) {
    const int n = it * 32 + ty * 4 + r8;
    u16x8 u;
#pragma unroll
    for (int j = 0; j < 8; ++j) u[j] = bfbits(tile[8 * q8 + j][n]);
    *(u16x8*)((unsigned short*)Wtp + (size_t)(n0 + n) * K + k0 + 8 * q8) = u;
  }
}

// ---- 256x256 MFMA GEMM, 4-half-unit rotation, cross-phase read-ahead ------
// (R11 pipeline + T5 setprio around MFMA clusters.)
// KLEN = K-slice length; blockIdx.z selects slice (kbase byte offset).
// SCATTER epilogue (stage-3 split-K): partial = g*(acc + bias@z==0), written
// to ybuf4[(z*2 + (tok_k&1))][token][col] — disjoint, no atomics.

#define BARRIER() asm volatile("s_barrier" ::: "memory")
#define LGKM(n) { asm volatile("s_waitcnt lgkmcnt(" #n ")" ::: "memory"); __builtin_amdgcn_sched_barrier(0); }
#define VMC(n)  { asm volatile("s_waitcnt vmcnt(" #n ")" ::: "memory"); __builtin_amdgcn_sched_barrier(0); }

template<bool GELU, bool OUTBF, bool SCATTER>
__global__ __launch_bounds__(512) void ffn_gemm8(
    const __hip_bfloat16* __restrict__ A,
    const __hip_bfloat16* __restrict__ Bt,
    const float* __restrict__ bias,
    void* __restrict__ Cout,
    const int* __restrict__ counts,
    const int* __restrict__ offsets,
    const int* __restrict__ tmap,
    const float* __restrict__ gate_slot,
    const int* __restrict__ tok_k,
    int K, int N, int KLEN)
{
  const int me = tmap[blockIdx.y];
  if (me < 0) return;
  const int e  = me >> 16;
  const int m0 = (me & 0xffff) << 8;
  const int cnt = counts[e];
  const int seg = offsets[e];
  const int n0 = blockIdx.x * 256;
  const int kbase = blockIdx.z * KLEN * 2;   // byte offset of this K-slice

  __shared__ char lds[131072];

  const int tid = threadIdx.x;
  const int wave = tid >> 6, lane = tid & 63;
  const int wm = wave >> 2, wn = wave & 3;

  const size_t KB = (size_t)K * 2;           // global row stride bytes
  const char* Ag = (const char*)(A + (size_t)(seg + m0) * K);
  const char* Bg = (const char*)(Bt + (size_t)e * N * K + (size_t)n0 * K);

  const int s_r  = tid >> 2;                                    // 0..127
  const int s_cb = ((tid & 3) * 16) ^ (((s_r >> 1) & 3) << 4);  // src pre-swizzle

  auto S = [&](int x) {
    const int ub = (x & 3) * 32768;
    const int kbyte = kbase + x * 64;
    const char* sa = Ag + (size_t)s_r * KB + kbyte + s_cb;
    const char* sb = Bg + (size_t)s_r * KB + kbyte + s_cb;
    __builtin_amdgcn_global_load_lds(
        (const __attribute__((address_space(1))) void*)sa,
        (__attribute__((address_space(3))) void*)(lds + ub + tid * 16), 16, 0, 0);
    __builtin_amdgcn_global_load_lds(
        (const __attribute__((address_space(1))) void*)(sa + 128 * KB),
        (__attribute__((address_space(3))) void*)(lds + ub + 8192 + tid * 16), 16, 0, 0);
    __builtin_amdgcn_global_load_lds(
        (const __attribute__((address_space(1))) void*)sb,
        (__attribute__((address_space(3))) void*)(lds + ub + 16384 + tid * 16), 16, 0, 0);
    __builtin_amdgcn_global_load_lds(
        (const __attribute__((address_space(1))) void*)(sb + 128 * KB),
        (__attribute__((address_space(3))) void*)(lds + ub + 16384 + 8192 + tid * 16), 16, 0, 0);
  };

  const int fr    = lane & 15;
  const int coff  = ((lane >> 4) * 16) ^ (((fr >> 1) & 3) << 4);
  const int aoff0 = (wm * 128 + fr) * 64 + coff;
  const int boff0 = 16384 + (wn * 64 + fr) * 64 + coff;

  f32x4 acc[8][4];
#pragma unroll
  for (int i = 0; i < 8; ++i)
#pragma unroll
    for (int j = 0; j < 4; ++j)
      acc[i][j] = (f32x4){0.f, 0.f, 0.f, 0.f};

  const int NPH = KLEN >> 5;

  bf16x8 aE[8], bE[4], aO[8], bO[4];

#define RD(x, as, bs) {                                             \
    const char* ub_ = lds + ((x) & 3) * 32768;                      \
    _Pragma("unroll")                                               \
    for (int m_ = 0; m_ < 8; ++m_)                                  \
      as[m_] = *(const bf16x8*)(ub_ + aoff0 + m_ * 1024);           \
    _Pragma("unroll")                                               \
    for (int n_ = 0; n_ < 4; ++n_)                                  \
      bs[n_] = *(const bf16x8*)(ub_ + boff0 + n_ * 1024); }

#define MM(as, bs) {                                                \
    __builtin_amdgcn_s_setprio(1);                                  \
    _Pragma("unroll")                                               \
    for (int m_ = 0; m_ < 8; ++m_)                                  \
      _Pragma("unroll")                                             \
      for (int n_ = 0; n_ < 4; ++n_)                                \
        acc[m_][n_] = __builtin_amdgcn_mfma_f32_16x16x32_bf16(      \
            as[m_], bs[n_], acc[m_][n_], 0, 0, 0);                  \
    __builtin_amdgcn_s_setprio(0); }

  S(0); S(1);
  VMC(4);
  BARRIER();

  RD(0, aE, bE);
  S(2);
  VMC(4);
  BARRIER();

  RD(1, aO, bO);
  S(3);
  LGKM(12);
  MM(aE, bE);
  VMC(4);
  BARRIER();

  for (int p = 2; p < NPH; p += 2) {
    RD(p, aE, bE);
    S(p + 2 < NPH ? p + 2 : NPH - 1);
    LGKM(12);
    MM(aO, bO);
    VMC(4);
    BARRIER();
    RD(p + 1, aO, bO);
    S(p + 3 < NPH ? p + 3 : NPH - 1);
    LGKM(12);
    MM(aE, bE);
    VMC(4);
    BARRIER();
  }

  LGKM(0);
  MM(aO, bO);

#undef RD
#undef MM

  // ---- epilogue: C/D map col=lane&15, row=(lane>>4)*4+r  [m89-verified]
#pragma unroll
  for (int mf = 0; mf < 8; ++mf) {
#pragma unroll
    for (int r2 = 0; r2 < 4; ++r2) {
      const int gm = m0 + wm * 128 + mf * 16 + (lane >> 4) * 4 + r2;
      if (gm >= cnt) continue;
      if (SCATTER) {
        const int s = seg + gm;
        const float g = gate_slot[s];
        const int tk = tok_k[s];
        float* dst = (float*)Cout +
            ((size_t)(blockIdx.z * 2 + (tk & 1)) * TOK + (size_t)(tk >> 1)) * EMB;
        const bool addb = (blockIdx.z == 0);
#pragma unroll
        for (int nf = 0; nf < 4; ++nf) {
          const int gcol = n0 + wn * 64 + nf * 16 + fr;
          dst[gcol] = g * (acc[mf][nf][r2] + (addb ? bias[(size_t)e * N + gcol] : 0.f));
        }
      } else {
#pragma unroll
        for (int nf = 0; nf < 4; ++nf) {
          const int gcol = n0 + wn * 64 + nf * 16 + fr;
          float v = acc[mf][nf][r2] + bias[(size_t)e * N + gcol];
          if (GELU) v = 0.5f * v * (1.0f + erff(v * 0.70710678118654752f));
          if (OUTBF)
            ((__hip_bfloat16*)Cout)[(size_t)(seg + gm) * N + gcol] = __float2bfloat16(v);
          else
            ((float*)Cout)[(size_t)(seg + gm) * N + gcol] = v;
        }
      }
    }
  }
}

// out = (y00+y01) + (y10+y11)  (token-indexed, fully coalesced)
__global__ __launch_bounds__(256) void k_combine4(const float* __restrict__ ybuf4,
                                                  float* __restrict__ out)
{
  const size_t stride = (size_t)TOK * EMB;
  const size_t total = stride / 4;
  for (size_t i = blockIdx.x * 256 + threadIdx.x; i < total; i += (size_t)gridDim.x * 256) {
    const float4 a = ((const float4*)ybuf4)[i];
    const float4 b = ((const float4*)(ybuf4 + stride))[i];
    const float4 c = ((const float4*)(ybuf4 + 2 * stride))[i];
    const float4 d = ((const float4*)(ybuf4 + 3 * stride))[i];
    float4 o;
    o.x = (a.x + b.x) + (c.x + d.x);
    o.y = (a.y + b.y) + (c.y + d.y);
    o.z = (a.z + b.z) + (c.z + d.z);
    o.w = (a.w + b.w) + (c.w + d.w);
    ((float4*)out)[i] = o;
  }
}

// ---------------- launch ----------------

extern "C" void kernel_launch(void* const* d_in, const int* in_sizes, int n_in,
                              void* d_out, int out_size, void* d_ws, size_t ws_size,
                              hipStream_t stream)
{
  const float* x  = (const float*)d_in[0];
  const float* Wg = (const float*)d_in[1];
  const float* bg = (const float*)d_in[2];
  const float* W1 = (const float*)d_in[3];
  const float* b1 = (const float*)d_in[4];
  const float* W2 = (const float*)d_in[5];
  const float* b2 = (const float*)d_in[6];
  const float* W3 = (const float*)d_in[7];
  const float* b3 = (const float*)d_in[8];
  float* out = (float*)d_out;

  char* ws = (char*)d_ws;
  size_t off = 0;
  auto alloc = [&](size_t bytes) -> void* {
    void* p = ws + off;
    off = (off + bytes + 255) & ~(size_t)255;
    return p;
  };

  int*   counts    = (int*)alloc(NE * 4);
  int*   fill      = (int*)alloc(NE * 4);
  int*   offsets   = (int*)alloc((NE + 1) * 4);
  int*   tmap      = (int*)alloc(MAXTILES * 4);
  int*   eidx      = (int*)alloc((size_t)TOK * 2 * 4);
  float* gates     = (float*)alloc((size_t)TOK * 2 * 4);
  int*   route_tok = (int*)alloc((size_t)SLOTS * 4);
  float* gate_slot = (float*)alloc((size_t)(SLOTS + SLACK) * 4);
  int*   tok_k     = (int*)alloc((size_t)(SLOTS + SLACK) * 4);
  __hip_bfloat16* Wb1 = (__hip_bfloat16*)alloc((size_t)NE * EMB  * HID  * 2);
  __hip_bfloat16* Wb2 = (__hip_bfloat16*)alloc((size_t)NE * HID  * HID2 * 2);
  __hip_bfloat16* Wb3 = (__hip_bfloat16*)alloc((size_t)NE * HID2 * EMB  * 2);
  __hip_bfloat16* xg  = (__hip_bfloat16*)alloc((size_t)(SLOTS + SLACK) * EMB  * 2);
  __hip_bfloat16* h1  = (__hip_bfloat16*)alloc((size_t)(SLOTS + SLACK) * HID  * 2);
  __hip_bfloat16* h2  = (__hip_bfloat16*)alloc((size_t)(SLOTS + SLACK) * HID2 * 2);
  float*          ybuf4 = (float*)alloc((size_t)4 * TOK * EMB * 4);
  (void)ws_size; (void)in_sizes; (void)n_in; (void)out_size;

  k_init<<<1, 64, 0, stream>>>(counts, fill);
  k_gating<<<TOK / 4, 256, 0, stream>>>(x, Wg, bg, eidx, gates);
  k_count<<<SLOTS / 512, 256, 0, stream>>>(eidx, counts);
  k_offsets<<<1, 1, 0, stream>>>(counts, offsets, tmap);
  k_route<<<TOK / 256, 256, 0, stream>>>(eidx, fill, offsets, route_tok,
                                         gate_slot, tok_k, gates);
  k_gather<<<SLOTS / 4, 256, 0, stream>>>(x, route_tok, xg);

  k_transpose_all<<<NT1 + NT2 + NT3, dim3(32, 8), 0, stream>>>(W1, W2, W3, Wb1, Wb2, Wb3);

  ffn_gemm8<true,  true,  false><<<dim3(HID  / 256, MAXTILES), 512, 0, stream>>>(
      xg, Wb1, b1, h1, counts, offsets, tmap, nullptr, nullptr, EMB,  HID,  EMB);
  ffn_gemm8<true,  true,  false><<<dim3(HID2 / 256, MAXTILES), 512, 0, stream>>>(
      h1, Wb2, b2, h2, counts, offsets, tmap, nullptr, nullptr, HID,  HID2, HID);
  ffn_gemm8<false, false, true ><<<dim3(EMB  / 256, MAXTILES, 2), 512, 0, stream>>>(
      h2, Wb3, b3, ybuf4, counts, offsets, tmap, gate_slot, tok_k, HID2, EMB, HID2 / 2);

  k_combine4<<<2048, 256, 0, stream>>>(ybuf4, out);
}

// Round 14
// 2450.952 us; speedup vs baseline: 1.1203x; 1.0274x over previous
//
#include <hip/hip_runtime.h>
#include <hip/hip_bf16.h>

#define EMB 768
#define HID 3072
#define HID2 6144
#define NE 8
#define TOK 16384    // B*N = 8*2048
#define SLOTS 32768  // TOK * top-2
#define SLACK 256    // tail-read slack rows (M-tile 256 may overrun by 255)
#define MAXTILES 136 // max active M-tiles: 128 + (NE-1) partials

typedef __attribute__((ext_vector_type(8))) short bf16x8;
typedef __attribute__((ext_vector_type(4))) float f32x4;

__device__ __forceinline__ unsigned short bfbits(float f) {
  __hip_bfloat16 h = __float2bfloat16(f);
  return __builtin_bit_cast(unsigned short, h);
}

// ---------------- init / gating / routing ----------------

__global__ void k_init(int* counts, int* fill) {
  if (threadIdx.x < NE) { counts[threadIdx.x] = 0; fill[threadIdx.x] = 0; }
}

__global__ __launch_bounds__(256) void k_gating(
    const float* __restrict__ x, const float* __restrict__ Wg,
    const float* __restrict__ bg, int* __restrict__ eidx,
    float* __restrict__ gates)
{
  const int wave = threadIdx.x >> 6, lane = threadIdx.x & 63;
  const int t = blockIdx.x * 4 + wave;
  const float* xr = x + (size_t)t * EMB;
  float p[NE];
#pragma unroll
  for (int e = 0; e < NE; ++e) p[e] = 0.f;
  for (int k = lane; k < EMB; k += 64) {
    const float xv = xr[k];
    const float* wr = Wg + (size_t)k * NE;
#pragma unroll
    for (int e = 0; e < NE; ++e) p[e] += xv * wr[e];
  }
#pragma unroll
  for (int e = 0; e < NE; ++e) {
#pragma unroll
    for (int o = 32; o > 0; o >>= 1) p[e] += __shfl_xor(p[e], o);
    p[e] += bg[e];
  }
  float v0 = -1e30f, v1 = -1e30f; int i0 = 0, i1 = 0;
#pragma unroll
  for (int e = 0; e < NE; ++e) {
    const float v = p[e];
    if (v > v0)      { v1 = v0; i1 = i0; v0 = v; i0 = e; }
    else if (v > v1) { v1 = v;  i1 = e; }
  }
  const float ex = expf(v1 - v0);
  const float g0 = 1.f / (1.f + ex);
  const float g1 = 1.f - g0;
  if (lane == 0) {
    eidx[2*t] = i0; eidx[2*t+1] = i1;
    gates[2*t] = g0; gates[2*t+1] = g1;
  }
}

__global__ __launch_bounds__(256) void k_count(const int* __restrict__ eidx,
                                               int* __restrict__ counts)
{
  __shared__ int bins[NE];
  if (threadIdx.x < NE) bins[threadIdx.x] = 0;
  __syncthreads();
  const int base = blockIdx.x * 512 + threadIdx.x * 2;
  atomicAdd(&bins[eidx[base]], 1);
  atomicAdd(&bins[eidx[base + 1]], 1);
  __syncthreads();
  if (threadIdx.x < NE) atomicAdd(&counts[threadIdx.x], bins[threadIdx.x]);
}

__global__ void k_offsets(const int* __restrict__ counts, int* __restrict__ offsets,
                          int* __restrict__ tmap)
{
  offsets[0] = 0;
  int idx = 0;
  for (int e = 0; e < NE; ++e) {
    offsets[e+1] = offsets[e] + counts[e];
    const int nt = (counts[e] + 255) >> 8;
    for (int i = 0; i < nt; ++i) tmap[idx++] = (e << 16) | i;
  }
  for (; idx < MAXTILES; ++idx) tmap[idx] = -1;
}

__global__ __launch_bounds__(256) void k_route(
    const int* __restrict__ eidx, int* __restrict__ fill,
    const int* __restrict__ offsets, int* __restrict__ route_tok,
    float* __restrict__ gate_slot, int* __restrict__ tok_k,
    const float* __restrict__ gates)
{
  __shared__ int bins[NE], base[NE];
  const int tid = threadIdx.x;
  if (tid < NE) bins[tid] = 0;
  __syncthreads();
  const int t = blockIdx.x * 256 + tid;
  int e0 = eidx[2*t], e1 = eidx[2*t+1];
  int lp0 = atomicAdd(&bins[e0], 1);
  int lp1 = atomicAdd(&bins[e1], 1);
  __syncthreads();
  if (tid < NE) base[tid] = atomicAdd(&fill[tid], bins[tid]);
  __syncthreads();
  const int s0 = offsets[e0] + base[e0] + lp0;
  const int s1 = offsets[e1] + base[e1] + lp1;
  route_tok[s0] = t;          route_tok[s1] = t;
  gate_slot[s0] = gates[2*t]; gate_slot[s1] = gates[2*t+1];
  tok_k[s0] = 2*t;            tok_k[s1] = 2*t + 1;
}

__global__ __launch_bounds__(256) void k_gather(
    const float* __restrict__ x, const int* __restrict__ route_tok,
    __hip_bfloat16* __restrict__ xg)
{
  const int w = threadIdx.x >> 6, lane = threadIdx.x & 63;
  const int s = blockIdx.x * 4 + w;
  const int t = route_tok[s];
  const float4* src = (const float4*)(x + (size_t)t * EMB);
  unsigned short* dst = (unsigned short*)xg + (size_t)s * EMB;
#pragma unroll
  for (int i = 0; i < 3; ++i) {
    const float4 v = src[lane + 64 * i];
    ushort4 u;
    u.x = bfbits(v.x); u.y = bfbits(v.y); u.z = bfbits(v.z); u.w = bfbits(v.w);
    *(ushort4*)(dst + (lane + 64 * i) * 4) = u;
  }
}

// unified fp32 [K,N] -> bf16 [N,K] transpose, 64x64 tiles
#define NT1 (NE * (HID  / 64) * (EMB  / 64))   // 4608
#define NT2 (NE * (HID2 / 64) * (HID  / 64))   // 36864
#define NT3 (NE * (EMB  / 64) * (HID2 / 64))   // 9216

typedef __attribute__((ext_vector_type(8))) unsigned short u16x8;

__global__ __launch_bounds__(256) void k_transpose_all(
    const float* __restrict__ W1, const float* __restrict__ W2,
    const float* __restrict__ W3, __hip_bfloat16* __restrict__ Wb1,
    __hip_bfloat16* __restrict__ Wb2, __hip_bfloat16* __restrict__ Wb3)
{
  __shared__ float tile[64][65];   // [k][n]
  int bid = blockIdx.x;
  const float* W; __hip_bfloat16* Wt; int K, N;
  if (bid < NT1)              { W = W1; Wt = Wb1; K = EMB;  N = HID;  }
  else if (bid < NT1 + NT2)   { W = W2; Wt = Wb2; K = HID;  N = HID2; bid -= NT1; }
  else                        { W = W3; Wt = Wb3; K = HID2; N = EMB;  bid -= NT1 + NT2; }
  const int ntn = N >> 6, ntk = K >> 6;
  const int e  = bid / (ntn * ntk);
  const int rem = bid - e * (ntn * ntk);
  const int k0 = (rem / ntn) << 6;
  const int n0 = (rem % ntn) << 6;

  const float* Wp = W + (size_t)e * K * N;
  __hip_bfloat16* Wtp = Wt + (size_t)e * K * N;
  const int tx = threadIdx.x, ty = threadIdx.y;   // 32 x 8

  const int q = tx & 15, rsub = tx >> 4;
#pragma unroll
  for (int it = 0; it < 4; ++it) {
    const int r = it * 16 + ty * 2 + rsub;
    const float4 v = *(const float4*)(Wp + (size_t)(k0 + r) * N + n0 + 4 * q);
    tile[r][4 * q]     = v.x;
    tile[r][4 * q + 1] = v.y;
    tile[r][4 * q + 2] = v.z;
    tile[r][4 * q + 3] = v.w;
  }
  __syncthreads();
  const int q8 = tx & 7, r8 = tx >> 3;
#pragma unroll
  for (int it = 0; it < 2; ++it) {
    const int n = it * 32 + ty * 4 + r8;
    u16x8 u;
#pragma unroll
    for (int j = 0; j < 8; ++j) u[j] = bfbits(tile[8 * q8 + j][n]);
    *(u16x8*)((unsigned short*)Wtp + (size_t)(n0 + n) * K + k0 + 8 * q8) = u;
  }
}

// ---- 256x256 MFMA GEMM, 5-unit rotation, 3-ahead staging pipeline --------
// A: bf16 [slots, K] (per-expert segments); Bt: bf16 [NE, N, K].
// BM=BN=256, 8 waves (2M x 4N), per-wave 128x64 C. Half = 32 k's.
// LDS = 5 units x 32KB = 160KB (full CU pool); half H_x lives in unit x%5.
// Phase p: RD(H_p) [published at bar(p-1)]; LGKM(12) [drains R(H_{p-1}) of
// THIS wave before its unit is overwritten]; S(H_{p+3}) -> unit (p-2)%5
// [all waves' R(H_{p-2}) drained at their LGKM in phase p-1 + barrier];
// MFMA(H_{p-1}); VMC(8) [drains S(H_{p+1}), keeps S(p+2),S(p+3) = 12KB
// in flight]; s_barrier [publishes H_{p+1}].  Tail S clamps restage
// identical bytes (benign). Swizzle (R4/R6-verified conflict-free):
// slot ^= ((row>>1)&3)<<4 on global SOURCE + ds_read addr.
// SCATTER epilogue (stage-3): ybuf2[tok_k&1][token][col], no atomics.

#define BARRIER() asm volatile("s_barrier" ::: "memory")
#define LGKM(n) { asm volatile("s_waitcnt lgkmcnt(" #n ")" ::: "memory"); __builtin_amdgcn_sched_barrier(0); }
#define VMC(n)  { asm volatile("s_waitcnt vmcnt(" #n ")" ::: "memory"); __builtin_amdgcn_sched_barrier(0); }

template<bool GELU, bool OUTBF, bool SCATTER>
__global__ __launch_bounds__(512) void ffn_gemm8(
    const __hip_bfloat16* __restrict__ A,
    const __hip_bfloat16* __restrict__ Bt,
    const float* __restrict__ bias,
    void* __restrict__ Cout,
    const int* __restrict__ counts,
    const int* __restrict__ offsets,
    const int* __restrict__ tmap,
    const float* __restrict__ gate_slot,
    const int* __restrict__ tok_k,
    int K, int N)
{
  const int me = tmap[blockIdx.y];
  if (me < 0) return;
  const int e  = me >> 16;
  const int m0 = (me & 0xffff) << 8;
  const int cnt = counts[e];
  const int seg = offsets[e];
  const int n0 = blockIdx.x * 256;

  __shared__ char lds[163840];   // 5 x 32KB units

  const int tid = threadIdx.x;
  const int wave = tid >> 6, lane = tid & 63;
  const int wm = wave >> 2, wn = wave & 3;

  const size_t KB = (size_t)K * 2;           // global row stride bytes
  const char* Ag = (const char*)(A + (size_t)(seg + m0) * K);
  const char* Bg = (const char*)(Bt + (size_t)e * N * K + (size_t)n0 * K);

  const int s_r  = tid >> 2;                                    // 0..127
  const int s_cb = ((tid & 3) * 16) ^ (((s_r >> 1) & 3) << 4);  // src pre-swizzle

  auto S = [&](int x) {
    const int ub = (x % 5) * 32768;
    const int kbyte = x * 64;
    const char* sa = Ag + (size_t)s_r * KB + kbyte + s_cb;
    const char* sb = Bg + (size_t)s_r * KB + kbyte + s_cb;
    __builtin_amdgcn_global_load_lds(
        (const __attribute__((address_space(1))) void*)sa,
        (__attribute__((address_space(3))) void*)(lds + ub + tid * 16), 16, 0, 0);
    __builtin_amdgcn_global_load_lds(
        (const __attribute__((address_space(1))) void*)(sa + 128 * KB),
        (__attribute__((address_space(3))) void*)(lds + ub + 8192 + tid * 16), 16, 0, 0);
    __builtin_amdgcn_global_load_lds(
        (const __attribute__((address_space(1))) void*)sb,
        (__attribute__((address_space(3))) void*)(lds + ub + 16384 + tid * 16), 16, 0, 0);
    __builtin_amdgcn_global_load_lds(
        (const __attribute__((address_space(1))) void*)(sb + 128 * KB),
        (__attribute__((address_space(3))) void*)(lds + ub + 16384 + 8192 + tid * 16), 16, 0, 0);
  };

  const int fr    = lane & 15;
  const int coff  = ((lane >> 4) * 16) ^ (((fr >> 1) & 3) << 4);
  const int aoff0 = (wm * 128 + fr) * 64 + coff;
  const int boff0 = 16384 + (wn * 64 + fr) * 64 + coff;

  f32x4 acc[8][4];
#pragma unroll
  for (int i = 0; i < 8; ++i)
#pragma unroll
    for (int j = 0; j < 4; ++j)
      acc[i][j] = (f32x4){0.f, 0.f, 0.f, 0.f};

  const int NPH = K >> 5;   // 32-k halves; >= 24 for all stages

  bf16x8 aE[8], bE[4], aO[8], bO[4];

#define RD(x, as, bs) {                                             \
    const char* ub_ = lds + ((x) % 5) * 32768;                      \
    _Pragma("unroll")                                               \
    for (int m_ = 0; m_ < 8; ++m_)                                  \
      as[m_] = *(const bf16x8*)(ub_ + aoff0 + m_ * 1024);           \
    _Pragma("unroll")                                               \
    for (int n_ = 0; n_ < 4; ++n_)                                  \
      bs[n_] = *(const bf16x8*)(ub_ + boff0 + n_ * 1024); }

#define MM(as, bs) {                                                \
    __builtin_amdgcn_s_setprio(1);                                  \
    _Pragma("unroll")                                               \
    for (int m_ = 0; m_ < 8; ++m_)                                  \
      _Pragma("unroll")                                             \
      for (int n_ = 0; n_ < 4; ++n_)                                \
        acc[m_][n_] = __builtin_amdgcn_mfma_f32_16x16x32_bf16(      \
            as[m_], bs[n_], acc[m_][n_], 0, 0, 0);                  \
    __builtin_amdgcn_s_setprio(0); }

  // ---- prologue: stage H0,H1,H2; publish H0
  S(0); S(1); S(2);
  VMC(8);           // S(H0) landed; S(H1),S(H2) in flight
  BARRIER();        // publish H0

  // ---- phase 0: R(H0)->E; S(H3); publish H1
  RD(0, aE, bE);
  S(3);
  VMC(8);           // S(H1) landed
  BARRIER();        // publish H1

  // ---- phase 1: R(H1)->O; S(H4); MFMA(H0:E); publish H2
  RD(1, aO, bO);
  LGKM(12);         // R(H0) complete, R(H1) in flight
  S(4);
  MM(aE, bE);
  VMC(8);           // S(H2) landed
  BARRIER();        // publish H2

  // ---- steady phases p=2..NPH-1 (pairs: even->E, odd->O)
  for (int p = 2; p < NPH; p += 2) {
    RD(p, aE, bE);
    LGKM(12);
    S(p + 3 < NPH ? p + 3 : NPH - 1);
    MM(aO, bO);
    VMC(8);
    BARRIER();
    RD(p + 1, aO, bO);
    LGKM(12);
    S(p + 4 < NPH ? p + 4 : NPH - 1);
    MM(aE, bE);
    VMC(8);
    BARRIER();
  }

  // ---- epilogue phase: MFMA(H_{NPH-1}:O)
  LGKM(0);
  MM(aO, bO);

#undef RD
#undef MM

  // ---- epilogue: C/D map col=lane&15, row=(lane>>4)*4+r  [m89-verified]
#pragma unroll
  for (int mf = 0; mf < 8; ++mf) {
#pragma unroll
    for (int r2 = 0; r2 < 4; ++r2) {
      const int gm = m0 + wm * 128 + mf * 16 + (lane >> 4) * 4 + r2;
      if (gm >= cnt) continue;
      if (SCATTER) {
        const int s = seg + gm;
        const float g = gate_slot[s];
        const int tk = tok_k[s];
        float* dst = (float*)Cout + ((size_t)(tk & 1) * TOK + (size_t)(tk >> 1)) * EMB;
#pragma unroll
        for (int nf = 0; nf < 4; ++nf) {
          const int gcol = n0 + wn * 64 + nf * 16 + fr;
          dst[gcol] = g * (acc[mf][nf][r2] + bias[(size_t)e * N + gcol]);
        }
      } else {
#pragma unroll
        for (int nf = 0; nf < 4; ++nf) {
          const int gcol = n0 + wn * 64 + nf * 16 + fr;
          float v = acc[mf][nf][r2] + bias[(size_t)e * N + gcol];
          if (GELU) v = 0.5f * v * (1.0f + erff(v * 0.70710678118654752f));
          if (OUTBF)
            ((__hip_bfloat16*)Cout)[(size_t)(seg + gm) * N + gcol] = __float2bfloat16(v);
          else
            ((float*)Cout)[(size_t)(seg + gm) * N + gcol] = v;
        }
      }
    }
  }
}

// out = y0 + y1 (token-indexed, fully coalesced)
__global__ __launch_bounds__(256) void k_combine2(const float* __restrict__ ybuf2,
                                                  float* __restrict__ out)
{
  const size_t total = (size_t)TOK * EMB / 4;
  for (size_t i = blockIdx.x * 256 + threadIdx.x; i < total; i += (size_t)gridDim.x * 256) {
    const float4 a = ((const float4*)ybuf2)[i];
    const float4 b = ((const float4*)(ybuf2 + (size_t)TOK * EMB))[i];
    float4 o;
    o.x = a.x + b.x; o.y = a.y + b.y; o.z = a.z + b.z; o.w = a.w + b.w;
    ((float4*)out)[i] = o;
  }
}

// ---------------- launch ----------------

extern "C" void kernel_launch(void* const* d_in, const int* in_sizes, int n_in,
                              void* d_out, int out_size, void* d_ws, size_t ws_size,
                              hipStream_t stream)
{
  const float* x  = (const float*)d_in[0];
  const float* Wg = (const float*)d_in[1];
  const float* bg = (const float*)d_in[2];
  const float* W1 = (const float*)d_in[3];
  const float* b1 = (const float*)d_in[4];
  const float* W2 = (const float*)d_in[5];
  const float* b2 = (const float*)d_in[6];
  const float* W3 = (const float*)d_in[7];
  const float* b3 = (const float*)d_in[8];
  float* out = (float*)d_out;

  char* ws = (char*)d_ws;
  size_t off = 0;
  auto alloc = [&](size_t bytes) -> void* {
    void* p = ws + off;
    off = (off + bytes + 255) & ~(size_t)255;
    return p;
  };

  int*   counts    = (int*)alloc(NE * 4);
  int*   fill      = (int*)alloc(NE * 4);
  int*   offsets   = (int*)alloc((NE + 1) * 4);
  int*   tmap      = (int*)alloc(MAXTILES * 4);
  int*   eidx      = (int*)alloc((size_t)TOK * 2 * 4);
  float* gates     = (float*)alloc((size_t)TOK * 2 * 4);
  int*   route_tok = (int*)alloc((size_t)SLOTS * 4);
  float* gate_slot = (float*)alloc((size_t)(SLOTS + SLACK) * 4);
  int*   tok_k     = (int*)alloc((size_t)(SLOTS + SLACK) * 4);
  __hip_bfloat16* Wb1 = (__hip_bfloat16*)alloc((size_t)NE * EMB  * HID  * 2);
  __hip_bfloat16* Wb2 = (__hip_bfloat16*)alloc((size_t)NE * HID  * HID2 * 2);
  __hip_bfloat16* Wb3 = (__hip_bfloat16*)alloc((size_t)NE * HID2 * EMB  * 2);
  __hip_bfloat16* xg  = (__hip_bfloat16*)alloc((size_t)(SLOTS + SLACK) * EMB  * 2);
  __hip_bfloat16* h1  = (__hip_bfloat16*)alloc((size_t)(SLOTS + SLACK) * HID  * 2);
  __hip_bfloat16* h2  = (__hip_bfloat16*)alloc((size_t)(SLOTS + SLACK) * HID2 * 2);
  float*          ybuf2 = (float*)alloc((size_t)2 * TOK * EMB * 4);
  (void)ws_size; (void)in_sizes; (void)n_in; (void)out_size;

  k_init<<<1, 64, 0, stream>>>(counts, fill);
  k_gating<<<TOK / 4, 256, 0, stream>>>(x, Wg, bg, eidx, gates);
  k_count<<<SLOTS / 512, 256, 0, stream>>>(eidx, counts);
  k_offsets<<<1, 1, 0, stream>>>(counts, offsets, tmap);
  k_route<<<TOK / 256, 256, 0, stream>>>(eidx, fill, offsets, route_tok,
                                         gate_slot, tok_k, gates);
  k_gather<<<SLOTS / 4, 256, 0, stream>>>(x, route_tok, xg);

  k_transpose_all<<<NT1 + NT2 + NT3, dim3(32, 8), 0, stream>>>(W1, W2, W3, Wb1, Wb2, Wb3);

  ffn_gemm8<true,  true,  false><<<dim3(HID  / 256, MAXTILES), 512, 0, stream>>>(
      xg, Wb1, b1, h1, counts, offsets, tmap, nullptr, nullptr, EMB,  HID);
  ffn_gemm8<true,  true,  false><<<dim3(HID2 / 256, MAXTILES), 512, 0, stream>>>(
      h1, Wb2, b2, h2, counts, offsets, tmap, nullptr, nullptr, HID,  HID2);
  ffn_gemm8<false, false, true ><<<dim3(EMB  / 256, MAXTILES), 512, 0, stream>>>(
      h2, Wb3, b3, ybuf2, counts, offsets, tmap, gate_slot, tok_k, HID2, EMB);

  k_combine2<<<2048, 256, 0, stream>>>(ybuf2, out);
}

// Round 15
// 2410.524 us; speedup vs baseline: 1.1391x; 1.0168x over previous
//
#include <hip/hip_runtime.h>
#include <hip/hip_bf16.h>

#define EMB 768
#define HID 3072
#define HID2 6144
#define NE 8
#define TOK 16384    // B*N = 8*2048
#define SLOTS 32768  // TOK * top-2
#define SLACK 256    // tail-read slack rows (M-tile 256 may overrun by 255)
#define MAXTILES 136 // max active M-tiles: 128 + (NE-1) partials

typedef __attribute__((ext_vector_type(8))) short bf16x8;
typedef __attribute__((ext_vector_type(4))) float f32x4;

__device__ __forceinline__ unsigned short bfbits(float f) {
  __hip_bfloat16 h = __float2bfloat16(f);
  return __builtin_bit_cast(unsigned short, h);
}

// ---------------- init / gating / routing ----------------

__global__ void k_init(int* counts, int* fill) {
  if (threadIdx.x < NE) { counts[threadIdx.x] = 0; fill[threadIdx.x] = 0; }
}

__global__ __launch_bounds__(256) void k_gating(
    const float* __restrict__ x, const float* __restrict__ Wg,
    const float* __restrict__ bg, int* __restrict__ eidx,
    float* __restrict__ gates)
{
  const int wave = threadIdx.x >> 6, lane = threadIdx.x & 63;
  const int t = blockIdx.x * 4 + wave;
  const float* xr = x + (size_t)t * EMB;
  float p[NE];
#pragma unroll
  for (int e = 0; e < NE; ++e) p[e] = 0.f;
  for (int k = lane; k < EMB; k += 64) {
    const float xv = xr[k];
    const float* wr = Wg + (size_t)k * NE;
#pragma unroll
    for (int e = 0; e < NE; ++e) p[e] += xv * wr[e];
  }
#pragma unroll
  for (int e = 0; e < NE; ++e) {
#pragma unroll
    for (int o = 32; o > 0; o >>= 1) p[e] += __shfl_xor(p[e], o);
    p[e] += bg[e];
  }
  float v0 = -1e30f, v1 = -1e30f; int i0 = 0, i1 = 0;
#pragma unroll
  for (int e = 0; e < NE; ++e) {
    const float v = p[e];
    if (v > v0)      { v1 = v0; i1 = i0; v0 = v; i0 = e; }
    else if (v > v1) { v1 = v;  i1 = e; }
  }
  const float ex = expf(v1 - v0);
  const float g0 = 1.f / (1.f + ex);
  const float g1 = 1.f - g0;
  if (lane == 0) {
    eidx[2*t] = i0; eidx[2*t+1] = i1;
    gates[2*t] = g0; gates[2*t+1] = g1;
  }
}

__global__ __launch_bounds__(256) void k_count(const int* __restrict__ eidx,
                                               int* __restrict__ counts)
{
  __shared__ int bins[NE];
  if (threadIdx.x < NE) bins[threadIdx.x] = 0;
  __syncthreads();
  const int base = blockIdx.x * 512 + threadIdx.x * 2;
  atomicAdd(&bins[eidx[base]], 1);
  atomicAdd(&bins[eidx[base + 1]], 1);
  __syncthreads();
  if (threadIdx.x < NE) atomicAdd(&counts[threadIdx.x], bins[threadIdx.x]);
}

__global__ void k_offsets(const int* __restrict__ counts, int* __restrict__ offsets,
                          int* __restrict__ tmap)
{
  offsets[0] = 0;
  int idx = 0;
  for (int e = 0; e < NE; ++e) {
    offsets[e+1] = offsets[e] + counts[e];
    const int nt = (counts[e] + 255) >> 8;
    for (int i = 0; i < nt; ++i) tmap[idx++] = (e << 16) | i;
  }
  for (; idx < MAXTILES; ++idx) tmap[idx] = -1;
}

__global__ __launch_bounds__(256) void k_route(
    const int* __restrict__ eidx, int* __restrict__ fill,
    const int* __restrict__ offsets, int* __restrict__ route_tok,
    float* __restrict__ gate_slot, int* __restrict__ tok_k,
    const float* __restrict__ gates)
{
  __shared__ int bins[NE], base[NE];
  const int tid = threadIdx.x;
  if (tid < NE) bins[tid] = 0;
  __syncthreads();
  const int t = blockIdx.x * 256 + tid;
  int e0 = eidx[2*t], e1 = eidx[2*t+1];
  int lp0 = atomicAdd(&bins[e0], 1);
  int lp1 = atomicAdd(&bins[e1], 1);
  __syncthreads();
  if (tid < NE) base[tid] = atomicAdd(&fill[tid], bins[tid]);
  __syncthreads();
  const int s0 = offsets[e0] + base[e0] + lp0;
  const int s1 = offsets[e1] + base[e1] + lp1;
  route_tok[s0] = t;          route_tok[s1] = t;
  gate_slot[s0] = gates[2*t]; gate_slot[s1] = gates[2*t+1];
  tok_k[s0] = 2*t;            tok_k[s1] = 2*t + 1;
}

__global__ __launch_bounds__(256) void k_gather(
    const float* __restrict__ x, const int* __restrict__ route_tok,
    __hip_bfloat16* __restrict__ xg)
{
  const int w = threadIdx.x >> 6, lane = threadIdx.x & 63;
  const int s = blockIdx.x * 4 + w;
  const int t = route_tok[s];
  const float4* src = (const float4*)(x + (size_t)t * EMB);
  unsigned short* dst = (unsigned short*)xg + (size_t)s * EMB;
#pragma unroll
  for (int i = 0; i < 3; ++i) {
    const float4 v = src[lane + 64 * i];
    ushort4 u;
    u.x = bfbits(v.x); u.y = bfbits(v.y); u.z = bfbits(v.z); u.w = bfbits(v.w);
    *(ushort4*)(dst + (lane + 64 * i) * 4) = u;
  }
}

// unified fp32 [K,N] -> bf16 [N,K] transpose, 64x64 tiles
#define NT1 (NE * (HID  / 64) * (EMB  / 64))   // 4608
#define NT2 (NE * (HID2 / 64) * (HID  / 64))   // 36864
#define NT3 (NE * (EMB  / 64) * (HID2 / 64))   // 9216

typedef __attribute__((ext_vector_type(8))) unsigned short u16x8;

__global__ __launch_bounds__(256) void k_transpose_all(
    const float* __restrict__ W1, const float* __restrict__ W2,
    const float* __restrict__ W3, __hip_bfloat16* __restrict__ Wb1,
    __hip_bfloat16* __restrict__ Wb2, __hip_bfloat16* __restrict__ Wb3)
{
  __shared__ float tile[64][65];   // [k][n]
  int bid = blockIdx.x;
  const float* W; __hip_bfloat16* Wt; int K, N;
  if (bid < NT1)              { W = W1; Wt = Wb1; K = EMB;  N = HID;  }
  else if (bid < NT1 + NT2)   { W = W2; Wt = Wb2; K = HID;  N = HID2; bid -= NT1; }
  else                        { W = W3; Wt = Wb3; K = HID2; N = EMB;  bid -= NT1 + NT2; }
  const int ntn = N >> 6, ntk = K >> 6;
  const int e  = bid / (ntn * ntk);
  const int rem = bid - e * (ntn * ntk);
  const int k0 = (rem / ntn) << 6;
  const int n0 = (rem % ntn) << 6;

  const float* Wp = W + (size_t)e * K * N;
  __hip_bfloat16* Wtp = Wt + (size_t)e * K * N;
  const int tx = threadIdx.x, ty = threadIdx.y;   // 32 x 8

  const int q = tx & 15, rsub = tx >> 4;
#pragma unroll
  for (int it = 0; it < 4; ++it) {
    const int r = it * 16 + ty * 2 + rsub;
    const float4 v = *(const float4*)(Wp + (size_t)(k0 + r) * N + n0 + 4 * q);
    tile[r][4 * q]     = v.x;
    tile[r][4 * q + 1] = v.y;
    tile[r][4 * q + 2] = v.z;
    tile[r][4 * q + 3] = v.w;
  }
  __syncthreads();
  const int q8 = tx & 7, r8 = tx >> 3;
#pragma unroll
  for (int it = 0; it < 2; ++it) {
    const int n = it * 32 + ty * 4 + r8;
    u16x8 u;
#pragma unroll
    for (int j = 0; j < 8; ++j) u[j] = bfbits(tile[8 * q8 + j][n]);
    *(u16x8*)((unsigned short*)Wtp + (size_t)(n0 + n) * K + k0 + 8 * q8) = u;
  }
}

// ---- 256x256 MFMA GEMM, 4-half-unit rotation, cross-phase read-ahead ------
// (R11 pipeline + T5 setprio — best measured stage-2 config, R13 core.)
// SCATTER epilogue (stage-3): v = gate_slot[row]*(acc + bias); written to
// ybuf2[tok_k&1][token][col] — disjoint, no atomics, deterministic.

#define BARRIER() asm volatile("s_barrier" ::: "memory")
#define LGKM(n) { asm volatile("s_waitcnt lgkmcnt(" #n ")" ::: "memory"); __builtin_amdgcn_sched_barrier(0); }
#define VMC(n)  { asm volatile("s_waitcnt vmcnt(" #n ")" ::: "memory"); __builtin_amdgcn_sched_barrier(0); }

template<bool GELU, bool OUTBF, bool SCATTER>
__global__ __launch_bounds__(512) void ffn_gemm8(
    const __hip_bfloat16* __restrict__ A,
    const __hip_bfloat16* __restrict__ Bt,
    const float* __restrict__ bias,
    void* __restrict__ Cout,
    const int* __restrict__ counts,
    const int* __restrict__ offsets,
    const int* __restrict__ tmap,
    const float* __restrict__ gate_slot,
    const int* __restrict__ tok_k,
    int K, int N)
{
  const int me = tmap[blockIdx.y];
  if (me < 0) return;
  const int e  = me >> 16;
  const int m0 = (me & 0xffff) << 8;
  const int cnt = counts[e];
  const int seg = offsets[e];
  const int n0 = blockIdx.x * 256;

  __shared__ char lds[131072];

  const int tid = threadIdx.x;
  const int wave = tid >> 6, lane = tid & 63;
  const int wm = wave >> 2, wn = wave & 3;

  const size_t KB = (size_t)K * 2;           // global row stride bytes
  const char* Ag = (const char*)(A + (size_t)(seg + m0) * K);
  const char* Bg = (const char*)(Bt + (size_t)e * N * K + (size_t)n0 * K);

  const int s_r  = tid >> 2;                                    // 0..127
  const int s_cb = ((tid & 3) * 16) ^ (((s_r >> 1) & 3) << 4);  // src pre-swizzle

  auto S = [&](int x) {
    const int ub = (x & 3) * 32768;
    const int kbyte = x * 64;
    const char* sa = Ag + (size_t)s_r * KB + kbyte + s_cb;
    const char* sb = Bg + (size_t)s_r * KB + kbyte + s_cb;
    __builtin_amdgcn_global_load_lds(
        (const __attribute__((address_space(1))) void*)sa,
        (__attribute__((address_space(3))) void*)(lds + ub + tid * 16), 16, 0, 0);
    __builtin_amdgcn_global_load_lds(
        (const __attribute__((address_space(1))) void*)(sa + 128 * KB),
        (__attribute__((address_space(3))) void*)(lds + ub + 8192 + tid * 16), 16, 0, 0);
    __builtin_amdgcn_global_load_lds(
        (const __attribute__((address_space(1))) void*)sb,
        (__attribute__((address_space(3))) void*)(lds + ub + 16384 + tid * 16), 16, 0, 0);
    __builtin_amdgcn_global_load_lds(
        (const __attribute__((address_space(1))) void*)(sb + 128 * KB),
        (__attribute__((address_space(3))) void*)(lds + ub + 16384 + 8192 + tid * 16), 16, 0, 0);
  };

  const int fr    = lane & 15;
  const int coff  = ((lane >> 4) * 16) ^ (((fr >> 1) & 3) << 4);
  const int aoff0 = (wm * 128 + fr) * 64 + coff;
  const int boff0 = 16384 + (wn * 64 + fr) * 64 + coff;

  f32x4 acc[8][4];
#pragma unroll
  for (int i = 0; i < 8; ++i)
#pragma unroll
    for (int j = 0; j < 4; ++j)
      acc[i][j] = (f32x4){0.f, 0.f, 0.f, 0.f};

  const int NPH = K >> 5;

  bf16x8 aE[8], bE[4], aO[8], bO[4];

#define RD(x, as, bs) {                                             \
    const char* ub_ = lds + ((x) & 3) * 32768;                      \
    _Pragma("unroll")                                               \
    for (int m_ = 0; m_ < 8; ++m_)                                  \
      as[m_] = *(const bf16x8*)(ub_ + aoff0 + m_ * 1024);           \
    _Pragma("unroll")                                               \
    for (int n_ = 0; n_ < 4; ++n_)                                  \
      bs[n_] = *(const bf16x8*)(ub_ + boff0 + n_ * 1024); }

#define MM(as, bs) {                                                \
    __builtin_amdgcn_s_setprio(1);                                  \
    _Pragma("unroll")                                               \
    for (int m_ = 0; m_ < 8; ++m_)                                  \
      _Pragma("unroll")                                             \
      for (int n_ = 0; n_ < 4; ++n_)                                \
        acc[m_][n_] = __builtin_amdgcn_mfma_f32_16x16x32_bf16(      \
            as[m_], bs[n_], acc[m_][n_], 0, 0, 0);                  \
    __builtin_amdgcn_s_setprio(0); }

  S(0); S(1);
  VMC(4);
  BARRIER();

  RD(0, aE, bE);
  S(2);
  VMC(4);
  BARRIER();

  RD(1, aO, bO);
  S(3);
  LGKM(12);
  MM(aE, bE);
  VMC(4);
  BARRIER();

  for (int p = 2; p < NPH; p += 2) {
    RD(p, aE, bE);
    S(p + 2 < NPH ? p + 2 : NPH - 1);
    LGKM(12);
    MM(aO, bO);
    VMC(4);
    BARRIER();
    RD(p + 1, aO, bO);
    S(p + 3 < NPH ? p + 3 : NPH - 1);
    LGKM(12);
    MM(aE, bE);
    VMC(4);
    BARRIER();
  }

  LGKM(0);
  MM(aO, bO);

#undef RD
#undef MM

  // ---- epilogue: C/D map col=lane&15, row=(lane>>4)*4+r  [m89-verified]
#pragma unroll
  for (int mf = 0; mf < 8; ++mf) {
#pragma unroll
    for (int r2 = 0; r2 < 4; ++r2) {
      const int gm = m0 + wm * 128 + mf * 16 + (lane >> 4) * 4 + r2;
      if (gm >= cnt) continue;
      if (SCATTER) {
        const int s = seg + gm;
        const float g = gate_slot[s];
        const int tk = tok_k[s];
        float* dst = (float*)Cout + ((size_t)(tk & 1) * TOK + (size_t)(tk >> 1)) * EMB;
#pragma unroll
        for (int nf = 0; nf < 4; ++nf) {
          const int gcol = n0 + wn * 64 + nf * 16 + fr;
          dst[gcol] = g * (acc[mf][nf][r2] + bias[(size_t)e * N + gcol]);
        }
      } else {
#pragma unroll
        for (int nf = 0; nf < 4; ++nf) {
          const int gcol = n0 + wn * 64 + nf * 16 + fr;
          float v = acc[mf][nf][r2] + bias[(size_t)e * N + gcol];
          if (GELU) v = 0.5f * v * (1.0f + erff(v * 0.70710678118654752f));
          if (OUTBF)
            ((__hip_bfloat16*)Cout)[(size_t)(seg + gm) * N + gcol] = __float2bfloat16(v);
          else
            ((float*)Cout)[(size_t)(seg + gm) * N + gcol] = v;
        }
      }
    }
  }
}

// out = y0 + y1 (token-indexed, fully coalesced)
__global__ __launch_bounds__(256) void k_combine2(const float* __restrict__ ybuf2,
                                                  float* __restrict__ out)
{
  const size_t total = (size_t)TOK * EMB / 4;
  for (size_t i = blockIdx.x * 256 + threadIdx.x; i < total; i += (size_t)gridDim.x * 256) {
    const float4 a = ((const float4*)ybuf2)[i];
    const float4 b = ((const float4*)(ybuf2 + (size_t)TOK * EMB))[i];
    float4 o;
    o.x = a.x + b.x; o.y = a.y + b.y; o.z = a.z + b.z; o.w = a.w + b.w;
    ((float4*)out)[i] = o;
  }
}

// ---------------- launch ----------------

extern "C" void kernel_launch(void* const* d_in, const int* in_sizes, int n_in,
                              void* d_out, int out_size, void* d_ws, size_t ws_size,
                              hipStream_t stream)
{
  const float* x  = (const float*)d_in[0];
  const float* Wg = (const float*)d_in[1];
  const float* bg = (const float*)d_in[2];
  const float* W1 = (const float*)d_in[3];
  const float* b1 = (const float*)d_in[4];
  const float* W2 = (const float*)d_in[5];
  const float* b2 = (const float*)d_in[6];
  const float* W3 = (const float*)d_in[7];
  const float* b3 = (const float*)d_in[8];
  float* out = (float*)d_out;

  char* ws = (char*)d_ws;
  size_t off = 0;
  auto alloc = [&](size_t bytes) -> void* {
    void* p = ws + off;
    off = (off + bytes + 255) & ~(size_t)255;
    return p;
  };

  int*   counts    = (int*)alloc(NE * 4);
  int*   fill      = (int*)alloc(NE * 4);
  int*   offsets   = (int*)alloc((NE + 1) * 4);
  int*   tmap      = (int*)alloc(MAXTILES * 4);
  int*   eidx      = (int*)alloc((size_t)TOK * 2 * 4);
  float* gates     = (float*)alloc((size_t)TOK * 2 * 4);
  int*   route_tok = (int*)alloc((size_t)SLOTS * 4);
  float* gate_slot = (float*)alloc((size_t)(SLOTS + SLACK) * 4);
  int*   tok_k     = (int*)alloc((size_t)(SLOTS + SLACK) * 4);
  __hip_bfloat16* Wb1 = (__hip_bfloat16*)alloc((size_t)NE * EMB  * HID  * 2);
  __hip_bfloat16* Wb2 = (__hip_bfloat16*)alloc((size_t)NE * HID  * HID2 * 2);
  __hip_bfloat16* Wb3 = (__hip_bfloat16*)alloc((size_t)NE * HID2 * EMB  * 2);
  __hip_bfloat16* xg  = (__hip_bfloat16*)alloc((size_t)(SLOTS + SLACK) * EMB  * 2);
  __hip_bfloat16* h1  = (__hip_bfloat16*)alloc((size_t)(SLOTS + SLACK) * HID  * 2);
  __hip_bfloat16* h2  = (__hip_bfloat16*)alloc((size_t)(SLOTS + SLACK) * HID2 * 2);
  float*          ybuf2 = (float*)alloc((size_t)2 * TOK * EMB * 4);
  (void)ws_size; (void)in_sizes; (void)n_in; (void)out_size;

  k_init<<<1, 64, 0, stream>>>(counts, fill);
  k_gating<<<TOK / 4, 256, 0, stream>>>(x, Wg, bg, eidx, gates);
  k_count<<<SLOTS / 512, 256, 0, stream>>>(eidx, counts);
  k_offsets<<<1, 1, 0, stream>>>(counts, offsets, tmap);
  k_route<<<TOK / 256, 256, 0, stream>>>(eidx, fill, offsets, route_tok,
                                         gate_slot, tok_k, gates);
  k_gather<<<SLOTS / 4, 256, 0, stream>>>(x, route_tok, xg);

  k_transpose_all<<<NT1 + NT2 + NT3, dim3(32, 8), 0, stream>>>(W1, W2, W3, Wb1, Wb2, Wb3);

  ffn_gemm8<true,  true,  false><<<dim3(HID  / 256, MAXTILES), 512, 0, stream>>>(
      xg, Wb1, b1, h1, counts, offsets, tmap, nullptr, nullptr, EMB,  HID);
  ffn_gemm8<true,  true,  false><<<dim3(HID2 / 256, MAXTILES), 512, 0, stream>>>(
      h1, Wb2, b2, h2, counts, offsets, tmap, nullptr, nullptr, HID,  HID2);
  ffn_gemm8<false, false, true ><<<dim3(EMB  / 256, MAXTILES), 512, 0, stream>>>(
      h2, Wb3, b3, ybuf2, counts, offsets, tmap, gate_slot, tok_k, HID2, EMB);

  k_combine2<<<2048, 256, 0, stream>>>(ybuf2, out);
}